// Round 7
// baseline (2760.155 us; speedup 1.0000x reference)
//
#include <hip/hip_runtime.h>

typedef float f32x4 __attribute__((ext_vector_type(4)));
typedef _Float16 f16x8 __attribute__((ext_vector_type(8)));
typedef _Float16 f16x4 __attribute__((ext_vector_type(4)));

constexpr int kB = 128;     // batch
constexpr int kT = 512;     // time
constexpr int kD = 256;     // emb dim
constexpr int kG = 512;     // 4*H gates per direction
constexpr int kH = 128;     // hidden
constexpr int kK = 9;       // CRF states
constexpr int kSTART = 7;
constexpr int kSTOP = 8;
constexpr int kNB = 16;     // chains per LSTM workgroup
constexpr float kL2E = 1.4426950408889634f;   // log2(e)

// gi layout, f16:  [dirg = dir*8+g][t][q(4)][u(128)][r(16)]  (gates pre-scaled
// by log2e so activations use native exp2). Row stride = 8192 f16 = 16 KiB.
// hws (h output) ALIASES gi row head [0,2048): row t written only after row t
// consumed (4-step prefetch slack); plain (non-restrict) pointers keep the
// compiler honest about the alias.

// ---------------------------------------------------------------------------
// Kernel 1: embedding gather + input projection (f16 MFMA GEMM)
// ---------------------------------------------------------------------------
__global__ __launch_bounds__(256) void proj_kernel(
    const int* __restrict__ sentence, const int* __restrict__ lengths,
    const float* __restrict__ emb,
    const float* __restrict__ Wih_f, const float* __restrict__ b_f,
    const float* __restrict__ Wih_b, const float* __restrict__ b_b,
    _Float16* __restrict__ gi)
{
    __shared__ __align__(16) _Float16 smemA[128 * 256]; // rows=(t,chain), 512B
    __shared__ __align__(16) _Float16 smemW[128 * 256]; // rows=gate, 512B

    const int g  = blockIdx.x >> 6;
    const int tc = blockIdx.x & 63;
    if (tc * 8 >= lengths[g * 16]) return;   // whole 8-t chunk beyond group max
    const int tid = threadIdx.x;

    // ---- stage A once: row = t_local*16 + chain ----
    {
        const int row = tid >> 1;
        const int kb  = (tid & 1) << 7;
        const int b   = g * 16 + (row & 15);
        const int t   = tc * 8 + (row >> 4);
        const int vocab = sentence[b * kT + t];
        const float* src = emb + (size_t)vocab * kD + kb;
        const unsigned rowbyte = row * 512;
        const unsigned sw = (row & 7) << 4;
        #pragma unroll
        for (int c = 0; c < 16; ++c) {
            float4 x0 = *(const float4*)(src + c * 8);
            float4 x1 = *(const float4*)(src + c * 8 + 4);
            f16x8 pk;
            pk[0] = (_Float16)x0.x; pk[1] = (_Float16)x0.y;
            pk[2] = (_Float16)x0.z; pk[3] = (_Float16)x0.w;
            pk[4] = (_Float16)x1.x; pk[5] = (_Float16)x1.y;
            pk[6] = (_Float16)x1.z; pk[7] = (_Float16)x1.w;
            unsigned byteoff = rowbyte + ((unsigned)((kb + c * 8) * 2) ^ sw);
            *(f16x8*)((char*)smemA + byteoff) = pk;
        }
    }

    const int w    = tid >> 6;
    const int lane = tid & 63;
    const int wr = w >> 1, wc = w & 1;
    const int l15 = lane & 15, l4 = lane >> 4;

    for (int by = 0; by < 8; ++by) {
        const int dir = by >> 2;
        const int q   = by & 3;
        __syncthreads();     // previous compute done (and A staged, iter 0)
        // ---- stage W rows for this (dir,q) ----
        {
            const int row = tid >> 1;
            const int kb  = (tid & 1) << 7;
            const float* src = (dir == 0 ? Wih_f : Wih_b)
                               + (size_t)(q * 128 + row) * kD + kb;
            const unsigned rowbyte = row * 512;
            const unsigned sw = (row & 7) << 4;
            #pragma unroll
            for (int c = 0; c < 16; ++c) {
                float4 x0 = *(const float4*)(src + c * 8);
                float4 x1 = *(const float4*)(src + c * 8 + 4);
                f16x8 pk;
                pk[0] = (_Float16)x0.x; pk[1] = (_Float16)x0.y;
                pk[2] = (_Float16)x0.z; pk[3] = (_Float16)x0.w;
                pk[4] = (_Float16)x1.x; pk[5] = (_Float16)x1.y;
                pk[6] = (_Float16)x1.z; pk[7] = (_Float16)x1.w;
                unsigned byteoff = rowbyte + ((unsigned)((kb + c * 8) * 2) ^ sw);
                *(f16x8*)((char*)smemW + byteoff) = pk;
            }
        }
        __syncthreads();

        f32x4 zero = {0.f, 0.f, 0.f, 0.f};
        f32x4 acc[4][4];
        #pragma unroll
        for (int mf = 0; mf < 4; ++mf)
            #pragma unroll
            for (int nf = 0; nf < 4; ++nf) acc[mf][nf] = zero;

        #pragma unroll
        for (int kk = 0; kk < 8; ++kk) {
            f16x8 afr[4], bfr[4];
            #pragma unroll
            for (int mf = 0; mf < 4; ++mf) {
                int row = wr * 64 + mf * 16 + l15;
                unsigned byteoff = row * 512 +
                    ((unsigned)(kk * 64 + l4 * 16) ^ (unsigned)((row & 7) << 4));
                afr[mf] = *(const f16x8*)((const char*)smemA + byteoff);
            }
            #pragma unroll
            for (int nf = 0; nf < 4; ++nf) {
                int row = wc * 64 + nf * 16 + l15;
                unsigned byteoff = row * 512 +
                    ((unsigned)(kk * 64 + l4 * 16) ^ (unsigned)((row & 7) << 4));
                bfr[nf] = *(const f16x8*)((const char*)smemW + byteoff);
            }
            #pragma unroll
            for (int mf = 0; mf < 4; ++mf)
                #pragma unroll
                for (int nf = 0; nf < 4; ++nf)
                    acc[mf][nf] = __builtin_amdgcn_mfma_f32_16x16x32_f16(
                        afr[mf], bfr[nf], acc[mf][nf], 0, 0, 0);
        }

        // ---- epilogue: one f16x4 (8B) store per fragment, pre-scaled log2e --
        const float* biasp = (dir == 0) ? b_f : b_b;
        _Float16* dbase = gi + (size_t)(dir * 8 + g) * kT * 8192;
        #pragma unroll
        for (int nf = 0; nf < 4; ++nf) {
            int u = wc * 64 + nf * 16 + l15;
            float bias = biasp[q * 128 + u];
            #pragma unroll
            for (int mf = 0; mf < 4; ++mf) {
                int t = tc * 8 + wr * 4 + mf;
                f16x4 pk;
                #pragma unroll
                for (int rg = 0; rg < 4; ++rg)
                    pk[rg] = (_Float16)((acc[mf][nf][rg] + bias) * kL2E);
                *(f16x4*)(dbase + (size_t)t * 8192 + (q * 128 + u) * 16 + l4 * 4) = pk;
            }
        }
    }
}

// ---------------------------------------------------------------------------
// Kernel 2: persistent weight-stationary LSTM. 8 wgs x 1024 thr (16 waves):
// waves 0-7 = forward dir, waves 8-15 = backward dir of the SAME group.
// 4 waves/SIMD fill each other's latency bubbles; shared per-step barrier
// (same trip count both dirs). 4-phase unroll, 4-deep prefetch, counted
// barrier, exp2-form activation (gates pre-scaled by log2e).
// ---------------------------------------------------------------------------
__device__ inline void wg_barrier() {
    asm volatile("s_waitcnt lgkmcnt(0)" ::: "memory");
    __builtin_amdgcn_s_barrier();
    asm volatile("" ::: "memory");
}

#define LOADSET(GP, SS)                                                       \
    do {                                                                      \
        int tt = dir ? (smax - 1 - (SS)) : (SS);                              \
        tt = tt < 0 ? 0 : (tt >= smax ? smax - 1 : tt);                       \
        const _Float16* rp = glane + (size_t)tt * 8192;                       \
        GP##0 = *(const f16x4*)(rp);                                          \
        GP##1 = *(const f16x4*)(rp + 2048);                                   \
        GP##2 = *(const f16x4*)(rp + 4096);                                   \
        GP##3 = *(const f16x4*)(rp + 6144);                                   \
    } while (0)

#define ACTIVATE(reg, ACC0, ACC1, ACC2, ACC3)                                 \
    do {                                                                      \
        float i_ = ACC0, f_ = ACC1, g_ = ACC2, o_ = ACC3;                     \
        g_ = fminf(fmaxf(g_, -28.9f), 28.9f);                                 \
        float Ei = exp2f(-i_), Ef = exp2f(-f_);                               \
        float Eg = exp2f(-2.f * g_), Eo = exp2f(-o_);                         \
        float p  = (1.f - Eg) *                                               \
            __builtin_amdgcn_rcpf((1.f + Ei) * (1.f + Eg));                   \
        float cn = __builtin_amdgcn_rcpf(1.f + Ef) * cst[reg] + p;            \
        float cc = fminf(fmaxf(cn, -20.f), 20.f);                             \
        float Ec = exp2f(cc * -2.8853900817779268f);                          \
        float hn = (1.f - Ec) *                                               \
            __builtin_amdgcn_rcpf((1.f + Eo) * (1.f + Ec));                   \
        if (tb < lenr[reg]) { cst[reg] = cn; hst[reg] = hn; }                 \
    } while (0)

#define LSTM_BODY(PH, GP)                                                     \
    do {                                                                      \
        const int tb = dir ? (smax - 1 - (s + PH)) : (s + PH);                \
        f32x4 acc[4];                                                         \
        _Pragma("unroll")                                                     \
        for (int reg = 0; reg < 4; ++reg) {                                   \
            acc[0][reg] = (float)GP##0[reg];                                  \
            acc[1][reg] = (float)GP##1[reg];                                  \
            acc[2][reg] = (float)GP##2[reg];                                  \
            acc[3][reg] = (float)GP##3[reg];                                  \
        }                                                                     \
        LOADSET(GP, s + PH + 4);                                              \
        _Pragma("unroll")                                                     \
        for (int kk = 0; kk < 4; ++kk)                                        \
            _Pragma("unroll")                                                 \
            for (int q = 0; q < 4; ++q)                                       \
                acc[q] = __builtin_amdgcn_mfma_f32_16x16x32_f16(              \
                    afr[kk], bfr[q][kk], acc[q], 0, 0, 0);                    \
        f16x4 hpk;                                                            \
        _Pragma("unroll")                                                     \
        for (int reg = 0; reg < 4; ++reg) {                                   \
            ACTIVATE(reg, acc[0][reg], acc[1][reg], acc[2][reg], acc[3][reg]);\
            hpk[reg] = (_Float16)hst[reg];                                    \
            int rr = l4 * 4 + reg;                                            \
            unsigned bo = ((unsigned)(rr * 256 + u * 2)) ^                    \
                          (unsigned)((rr & 7) << 4);                          \
            *(_Float16*)((char*)hbuf[dir][(PH) & 1] + bo) = hpk[reg];         \
        }                                                                     \
        *(f16x4*)(hrow_base + (size_t)tb * 8192) = hpk;                       \
        wg_barrier();                                                         \
        {                                                                     \
            const unsigned sw2 = (unsigned)((l15 & 7) << 4);                  \
            _Pragma("unroll")                                                 \
            for (int kk = 0; kk < 4; ++kk) {                                  \
                unsigned bo = ((unsigned)(l15 * 256 + kk * 64 + l4 * 16)) ^   \
                              sw2;                                            \
                afr[kk] = *(const f16x8*)                                     \
                    ((const char*)hbuf[dir][(PH) & 1] + bo);                  \
            }                                                                 \
        }                                                                     \
    } while (0)

__global__ __launch_bounds__(1024) void lstm_kernel(
    const _Float16* gi, _Float16* hws, const int* __restrict__ lengths,
    const float* __restrict__ Whh_f, const float* __restrict__ Whh_b)
{
    const int g   = blockIdx.x;          // 0..7
    const int tid = threadIdx.x;
    const int w   = tid >> 6;            // 0..15
    const int dir = w >> 3;              // waves 0-7 fwd, 8-15 bwd
    const int wl  = w & 7;               // wave within direction
    const int l   = tid & 63;
    const int l15 = l & 15, l4 = l >> 4;

    __shared__ __align__(16) _Float16 hbuf[2][2][kNB * kH]; // [dir][parity]

    // ---- Whh B-fragments resident in VGPRs (scaled by log2e) ----
    const float* Whh = dir ? Whh_b : Whh_f;
    f16x8 bfr[4][4];
    #pragma unroll
    for (int q = 0; q < 4; ++q) {
        #pragma unroll
        for (int kk = 0; kk < 4; ++kk) {
            int n  = q * 128 + wl * 16 + l15;
            int k0 = kk * 32 + l4 * 8;
            const float* src = Whh + (size_t)n * kH + k0;
            float4 x0 = *(const float4*)(src);
            float4 x1 = *(const float4*)(src + 4);
            f16x8 v;
            v[0] = (_Float16)(x0.x * kL2E); v[1] = (_Float16)(x0.y * kL2E);
            v[2] = (_Float16)(x0.z * kL2E); v[3] = (_Float16)(x0.w * kL2E);
            v[4] = (_Float16)(x1.x * kL2E); v[5] = (_Float16)(x1.y * kL2E);
            v[6] = (_Float16)(x1.z * kL2E); v[7] = (_Float16)(x1.w * kL2E);
            bfr[q][kk] = v;
        }
    }

    int lenr[4];
    #pragma unroll
    for (int reg = 0; reg < 4; ++reg)
        lenr[reg] = lengths[g * kNB + l4 * 4 + reg];
    const int smax = lengths[g * kNB];   // same for both dirs -> aligned loops

    const int u = wl * 16 + l15;
    float cst[4] = {0.f, 0.f, 0.f, 0.f};
    float hst[4] = {0.f, 0.f, 0.f, 0.f};
    f16x8 afr[4];
    #pragma unroll
    for (int kk = 0; kk < 4; ++kk)
        #pragma unroll
        for (int j = 0; j < 8; ++j) afr[kk][j] = (_Float16)0.f;

    const _Float16* glane = gi + (size_t)(dir * 8 + g) * kT * 8192
                               + (size_t)(u * 16 + l4 * 4);
    _Float16* hrow_base = hws + (size_t)(dir * 8 + g) * kT * 8192
                              + (size_t)(tid & 511) * 4;

    f16x4 gA0, gA1, gA2, gA3, gB0, gB1, gB2, gB3;
    f16x4 gC0, gC1, gC2, gC3, gD0, gD1, gD2, gD3;
    {
        int s = 0;
        LOADSET(gA, 0); LOADSET(gB, 1); LOADSET(gC, 2); LOADSET(gD, 3);
        (void)s;
    }

    int s = 0;
    for (; s + 4 <= smax; s += 4) {
        LSTM_BODY(0, gA);
        LSTM_BODY(1, gB);
        LSTM_BODY(2, gC);
        LSTM_BODY(3, gD);
    }
    // ---- tail (<=3 steps) ----
    for (; s < smax; ++s) {
        const int tb = dir ? (smax - 1 - s) : s;
        const _Float16* rp = glane + (size_t)tb * 8192;
        f16x4 t0 = *(const f16x4*)(rp);
        f16x4 t1 = *(const f16x4*)(rp + 2048);
        f16x4 t2 = *(const f16x4*)(rp + 4096);
        f16x4 t3 = *(const f16x4*)(rp + 6144);
        f32x4 acc[4];
        #pragma unroll
        for (int reg = 0; reg < 4; ++reg) {
            acc[0][reg] = (float)t0[reg]; acc[1][reg] = (float)t1[reg];
            acc[2][reg] = (float)t2[reg]; acc[3][reg] = (float)t3[reg];
        }
        #pragma unroll
        for (int kk = 0; kk < 4; ++kk)
            #pragma unroll
            for (int q = 0; q < 4; ++q)
                acc[q] = __builtin_amdgcn_mfma_f32_16x16x32_f16(
                    afr[kk], bfr[q][kk], acc[q], 0, 0, 0);
        f16x4 hpk;
        #pragma unroll
        for (int reg = 0; reg < 4; ++reg) {
            ACTIVATE(reg, acc[0][reg], acc[1][reg], acc[2][reg], acc[3][reg]);
            hpk[reg] = (_Float16)hst[reg];
            int rr = l4 * 4 + reg;
            unsigned bo = ((unsigned)(rr * 256 + u * 2)) ^
                          (unsigned)((rr & 7) << 4);
            *(_Float16*)((char*)hbuf[dir][s & 1] + bo) = hpk[reg];
        }
        *(f16x4*)(hrow_base + (size_t)tb * 8192) = hpk;
        wg_barrier();
        {
            const unsigned sw2 = (unsigned)((l15 & 7) << 4);
            #pragma unroll
            for (int kk = 0; kk < 4; ++kk) {
                unsigned bo = ((unsigned)(l15 * 256 + kk * 64 + l4 * 16)) ^ sw2;
                afr[kk] = *(const f16x8*)((const char*)hbuf[dir][s & 1] + bo);
            }
        }
    }
}

// ---------------------------------------------------------------------------
// Kernel 2b: feats. wg per (g, t): stage both dir h-rows (4KB each) + Wt,
// 144 threads compute fsum[b][t][k] = hf.Wt[:, :128] + hb.Wt[:, 128:] + bt.
// ---------------------------------------------------------------------------
__global__ __launch_bounds__(256) void feats_kernel(
    const _Float16* __restrict__ hws, const float* __restrict__ Wt,
    const float* __restrict__ bt, float* __restrict__ fsum)
{
    __shared__ _Float16 hf[2048], hb[2048];
    __shared__ float wts[kK * 256];
    __shared__ float bts[kK];
    const int g = blockIdx.x >> 9;
    const int t = blockIdx.x & 511;
    const int tid = threadIdx.x;

    *(f16x8*)&hf[tid * 8] =
        *(const f16x8*)(hws + ((size_t)g * kT + t) * 8192 + tid * 8);
    *(f16x8*)&hb[tid * 8] =
        *(const f16x8*)(hws + ((size_t)(8 + g) * kT + t) * 8192 + tid * 8);
    for (int i = tid; i < kK * 256; i += 256) wts[i] = Wt[i];
    if (tid < kK) bts[tid] = bt[tid];
    __syncthreads();

    if (tid < 144) {
        const int k = tid >> 4;      // 0..8
        const int r = tid & 15;      // chain in group
        float acc = bts[k];
        #pragma unroll 8
        for (int uu = 0; uu < kH; ++uu) {
            int idx = (uu >> 4) * 256 + (r >> 2) * 64 + (uu & 15) * 4 + (r & 3);
            acc += (float)hf[idx] * wts[k * 256 + uu] +
                   (float)hb[idx] * wts[k * 256 + 128 + uu];
        }
        fsum[((size_t)(g * 16 + r) * kT + t) * kK + k] = acc;
    }
}

// ---------------------------------------------------------------------------
// Kernel 3: CRF Viterbi via max-plus matrix reduction tree.
// ---------------------------------------------------------------------------
__global__ __launch_bounds__(512) void viterbi_kernel(
    const int* __restrict__ lengths, const float* __restrict__ trans,
    const float* __restrict__ fsumg, float* __restrict__ out)
{
    constexpr float NEG = -1e30f;
    constexpr int RA = 0;
    constexpr int RB = 128 * 81;
    const int b = blockIdx.x;
    const int len = lengths[b];
    const int tid = threadIdx.x;

    __shared__ float tree[(128 + 64) * 81];
    __shared__ float fsum[kT * kK];
    __shared__ float trs[81];
    __shared__ float red[16];

    if (tid < 81) trs[tid] = trans[tid];
    for (int idx = tid; idx < len * kK; idx += 512)
        fsum[idx] = fsumg[(size_t)b * kT * kK + idx];
    __syncthreads();

    for (int task = tid; task < 128 * 9; task += 512) {
        int s = task / 9, j = task - s * 9;
        int tb = 4 * s;
        float uu[9];
        #pragma unroll
        for (int m = 0; m < 9; ++m)
            uu[m] = (tb < len) ? (trs[m * 9 + j] + fsum[tb * 9 + m])
                               : ((m == j) ? 0.f : NEG);
        #pragma unroll
        for (int q = 1; q < 4; ++q) {
            int t = tb + q;
            if (t < len) {
                float un[9];
                #pragma unroll
                for (int k = 0; k < 9; ++k) {
                    float v = trs[k * 9] + uu[0];
                    #pragma unroll
                    for (int m = 1; m < 9; ++m)
                        v = fmaxf(v, trs[k * 9 + m] + uu[m]);
                    un[k] = v + fsum[t * 9 + k];
                }
                #pragma unroll
                for (int k = 0; k < 9; ++k) uu[k] = un[k];
            }
        }
        #pragma unroll
        for (int k = 0; k < 9; ++k)
            tree[RA + s * 81 + k * 9 + j] = uu[k];
    }
    __syncthreads();

    int soff = RA, doff = RB;
    for (int np = 64; np >= 1; np >>= 1) {
        for (int idx = tid; idx < np * 81; idx += 512) {
            int s = idx / 81, o = idx - s * 81;
            int k = o / 9, j = o - k * 9;
            const float* A  = tree + soff + (2 * s + 1) * 81;
            const float* Bm = tree + soff + (2 * s) * 81;
            float v = A[k * 9] + Bm[j];
            #pragma unroll
            for (int m = 1; m < 9; ++m)
                v = fmaxf(v, A[k * 9 + m] + Bm[m * 9 + j]);
            tree[doff + s * 81 + o] = v;
        }
        int tmp = soff; soff = doff; doff = tmp;
        __syncthreads();
    }
    if (tid < kK) {
        int k = tid;
        float fv = tree[soff + k * 9 + kSTART];
        #pragma unroll
        for (int j = 0; j < 9; ++j)
            if (j != kSTART) fv = fmaxf(fv, tree[soff + k * 9 + j] - 10000.f);
        red[k] = fv + trs[kSTOP * 9 + k];
    }
    __syncthreads();
    if (tid == 0) {
        float m = red[0];
        #pragma unroll
        for (int k = 1; k < 9; ++k) m = fmaxf(m, red[k]);
        out[b] = m;
    }
}

// ---------------------------------------------------------------------------
extern "C" void kernel_launch(void* const* d_in, const int* in_sizes, int n_in,
                              void* d_out, int out_size, void* d_ws, size_t ws_size,
                              hipStream_t stream) {
    const int*   sentence = (const int*)d_in[0];
    const int*   lengths  = (const int*)d_in[1];
    const float* emb      = (const float*)d_in[2];
    const float* Wih_f    = (const float*)d_in[3];
    const float* Whh_f    = (const float*)d_in[4];
    const float* b_f      = (const float*)d_in[5];
    const float* Wih_b    = (const float*)d_in[6];
    const float* Whh_b    = (const float*)d_in[7];
    const float* b_b      = (const float*)d_in[8];
    const float* Wt       = (const float*)d_in[9];
    const float* bt       = (const float*)d_in[10];
    const float* trans    = (const float*)d_in[11];
    float* out = (float*)d_out;

    char* ws = (char*)d_ws;
    const size_t gi_bytes = (size_t)2 * kB * kT * kG * sizeof(_Float16); // 128 MiB
    _Float16* gi   = (_Float16*)ws;
    _Float16* hws  = (_Float16*)ws;                  // aliases gi row heads
    float*    fsum = (float*)(ws + gi_bytes);        // 2.25 MiB

    proj_kernel<<<512, 256, 0, stream>>>(sentence, lengths, emb,
                                         Wih_f, b_f, Wih_b, b_b, gi);
    lstm_kernel<<<8, 1024, 0, stream>>>(gi, hws, lengths, Whh_f, Whh_b);
    feats_kernel<<<4096, 256, 0, stream>>>(hws, Wt, bt, fsum);
    viterbi_kernel<<<128, 512, 0, stream>>>(lengths, trans, fsum, out);
}

// Round 8
// 816.190 us; speedup vs baseline: 3.3818x; 3.3818x over previous
//
#include <hip/hip_runtime.h>

typedef float f32x4 __attribute__((ext_vector_type(4)));
typedef _Float16 f16x8 __attribute__((ext_vector_type(8)));
typedef _Float16 f16x4 __attribute__((ext_vector_type(4)));

constexpr int kB = 128;     // batch
constexpr int kT = 512;     // time
constexpr int kD = 256;     // emb dim
constexpr int kG = 512;     // 4*H gates per direction
constexpr int kH = 128;     // hidden
constexpr int kK = 9;       // CRF states
constexpr int kSTART = 7;
constexpr int kSTOP = 8;
constexpr int kNB = 16;     // chains per LSTM workgroup

// gi layout, f16:  [dirg = dir*8+g][t][w(8)][q(4)][ul(16)][r(16)]
//   halfword offset in row = w*1024 + q*256 + ul*16 + r;  row = 8192 f16.
// Wave w of lstm reads EXACTLY [w*1024, w*1024+1024) of each row -> it stages
// its own chunk with 2x global_load_lds (16B/lane) and per-wave vmcnt works.
// hws (h output) aliases gi row head [0,2048): stores trail consumption.

// ---------------------------------------------------------------------------
// Kernel 1: embedding gather + input projection (f16 MFMA GEMM)
// ---------------------------------------------------------------------------
__global__ __launch_bounds__(256) void proj_kernel(
    const int* __restrict__ sentence, const int* __restrict__ lengths,
    const float* __restrict__ emb,
    const float* __restrict__ Wih_f, const float* __restrict__ b_f,
    const float* __restrict__ Wih_b, const float* __restrict__ b_b,
    _Float16* __restrict__ gi)
{
    __shared__ __align__(16) _Float16 smemA[128 * 256]; // rows=(t,chain), 512B
    __shared__ __align__(16) _Float16 smemW[128 * 256]; // rows=gate, 512B

    const int g  = blockIdx.x >> 6;
    const int tc = blockIdx.x & 63;
    if (tc * 8 >= lengths[g * 16]) return;   // whole 8-t chunk beyond group max
    const int tid = threadIdx.x;

    // ---- stage A once: row = t_local*16 + chain ----
    {
        const int row = tid >> 1;
        const int kb  = (tid & 1) << 7;
        const int b   = g * 16 + (row & 15);
        const int t   = tc * 8 + (row >> 4);
        const int vocab = sentence[b * kT + t];
        const float* src = emb + (size_t)vocab * kD + kb;
        const unsigned rowbyte = row * 512;
        const unsigned sw = (row & 7) << 4;
        #pragma unroll
        for (int c = 0; c < 16; ++c) {
            float4 x0 = *(const float4*)(src + c * 8);
            float4 x1 = *(const float4*)(src + c * 8 + 4);
            f16x8 pk;
            pk[0] = (_Float16)x0.x; pk[1] = (_Float16)x0.y;
            pk[2] = (_Float16)x0.z; pk[3] = (_Float16)x0.w;
            pk[4] = (_Float16)x1.x; pk[5] = (_Float16)x1.y;
            pk[6] = (_Float16)x1.z; pk[7] = (_Float16)x1.w;
            unsigned byteoff = rowbyte + ((unsigned)((kb + c * 8) * 2) ^ sw);
            *(f16x8*)((char*)smemA + byteoff) = pk;
        }
    }

    const int w    = tid >> 6;
    const int lane = tid & 63;
    const int wr = w >> 1, wc = w & 1;
    const int l15 = lane & 15, l4 = lane >> 4;

    for (int by = 0; by < 8; ++by) {
        const int dir = by >> 2;
        const int q   = by & 3;
        __syncthreads();     // previous compute done (and A staged, iter 0)
        // ---- stage W rows for this (dir,q) ----
        {
            const int row = tid >> 1;
            const int kb  = (tid & 1) << 7;
            const float* src = (dir == 0 ? Wih_f : Wih_b)
                               + (size_t)(q * 128 + row) * kD + kb;
            const unsigned rowbyte = row * 512;
            const unsigned sw = (row & 7) << 4;
            #pragma unroll
            for (int c = 0; c < 16; ++c) {
                float4 x0 = *(const float4*)(src + c * 8);
                float4 x1 = *(const float4*)(src + c * 8 + 4);
                f16x8 pk;
                pk[0] = (_Float16)x0.x; pk[1] = (_Float16)x0.y;
                pk[2] = (_Float16)x0.z; pk[3] = (_Float16)x0.w;
                pk[4] = (_Float16)x1.x; pk[5] = (_Float16)x1.y;
                pk[6] = (_Float16)x1.z; pk[7] = (_Float16)x1.w;
                unsigned byteoff = rowbyte + ((unsigned)((kb + c * 8) * 2) ^ sw);
                *(f16x8*)((char*)smemW + byteoff) = pk;
            }
        }
        __syncthreads();

        f32x4 zero = {0.f, 0.f, 0.f, 0.f};
        f32x4 acc[4][4];
        #pragma unroll
        for (int mf = 0; mf < 4; ++mf)
            #pragma unroll
            for (int nf = 0; nf < 4; ++nf) acc[mf][nf] = zero;

        #pragma unroll
        for (int kk = 0; kk < 8; ++kk) {
            f16x8 afr[4], bfr[4];
            #pragma unroll
            for (int mf = 0; mf < 4; ++mf) {
                int row = wr * 64 + mf * 16 + l15;
                unsigned byteoff = row * 512 +
                    ((unsigned)(kk * 64 + l4 * 16) ^ (unsigned)((row & 7) << 4));
                afr[mf] = *(const f16x8*)((const char*)smemA + byteoff);
            }
            #pragma unroll
            for (int nf = 0; nf < 4; ++nf) {
                int row = wc * 64 + nf * 16 + l15;
                unsigned byteoff = row * 512 +
                    ((unsigned)(kk * 64 + l4 * 16) ^ (unsigned)((row & 7) << 4));
                bfr[nf] = *(const f16x8*)((const char*)smemW + byteoff);
            }
            #pragma unroll
            for (int mf = 0; mf < 4; ++mf)
                #pragma unroll
                for (int nf = 0; nf < 4; ++nf)
                    acc[mf][nf] = __builtin_amdgcn_mfma_f32_16x16x32_f16(
                        afr[mf], bfr[nf], acc[mf][nf], 0, 0, 0);
        }

        // ---- epilogue: one f16x4 (8B) store per fragment, new row layout ----
        const float* biasp = (dir == 0) ? b_f : b_b;
        _Float16* dbase = gi + (size_t)(dir * 8 + g) * kT * 8192;
        #pragma unroll
        for (int nf = 0; nf < 4; ++nf) {
            int uu = wc * 64 + nf * 16 + l15;
            float bias = biasp[q * 128 + uu];
            int woff = (uu >> 4) * 1024 + q * 256 + (uu & 15) * 16 + l4 * 4;
            #pragma unroll
            for (int mf = 0; mf < 4; ++mf) {
                int t = tc * 8 + wr * 4 + mf;
                f16x4 pk;
                #pragma unroll
                for (int rg = 0; rg < 4; ++rg)
                    pk[rg] = (_Float16)(acc[mf][nf][rg] + bias);
                *(f16x4*)(dbase + (size_t)t * 8192 + woff) = pk;
            }
        }
    }
}

// ---------------------------------------------------------------------------
// Kernel 2: persistent weight-stationary LSTM. 16 wgs x 512 thr.
// gi staged via global_load_lds (vmcnt-counted, never drained by the barrier);
// per-wave chunk ownership; delayed h stores; __expf activation.
// ---------------------------------------------------------------------------
__device__ inline float sigm(float x) {
    return __builtin_amdgcn_rcpf(1.f + __expf(-x));
}
__device__ inline float tanh_(float x) {
    float t = __expf(-2.f * fabsf(x));
    float r = (1.f - t) * __builtin_amdgcn_rcpf(1.f + t);
    return x >= 0.f ? r : -r;
}

typedef const __attribute__((address_space(1))) unsigned int* gas1;
typedef __attribute__((address_space(3))) unsigned int* las3;

// Stage gi step SS into lbuf[BUF]: each wave stages its own 2KB chunk.
#define STAGE(BUF, SS)                                                        \
    do {                                                                      \
        int tt = dir ? (smax - 1 - (SS)) : (SS);                              \
        tt = tt < 0 ? 0 : (tt >= smax ? smax - 1 : tt);                       \
        const _Float16* gsrc = grow + (size_t)tt * 8192 + w * 1024 + l * 8;   \
        __builtin_amdgcn_global_load_lds((gas1)(const void*)gsrc,             \
            (las3)(void*)(&lbuf[BUF][w * 1024]), 16, 0, 0);                   \
        __builtin_amdgcn_global_load_lds((gas1)(const void*)(gsrc + 512),     \
            (las3)(void*)(&lbuf[BUF][w * 1024 + 512]), 16, 0, 0);             \
    } while (0)

#define LSTM_BODY(PH, HPKP, HPKC, DOSTORE)                                    \
    do {                                                                      \
        if (DOSTORE) { /* store PREVIOUS step's h (one-phase slack) */        \
            int tr = dir ? (smax - (s + PH)) : (s + PH - 1);                  \
            tr = tr < 0 ? 0 : (tr > 511 ? 511 : tr);                          \
            *(f16x4*)(hrow_base + (size_t)tr * 8192) = HPKP;                  \
        }                                                                     \
        asm volatile("s_waitcnt vmcnt(4)" ::: "memory");                      \
        const int tb = dir ? (smax - 1 - (s + PH)) : (s + PH);                \
        const _Float16* lb =                                                  \
            &lbuf[(s + PH) & 1][w * 1024 + l15 * 16 + l4 * 4];                \
        f16x4 c0 = *(const f16x4*)(lb);                                       \
        f16x4 c1 = *(const f16x4*)(lb + 256);                                 \
        f16x4 c2 = *(const f16x4*)(lb + 512);                                 \
        f16x4 c3 = *(const f16x4*)(lb + 768);                                 \
        f32x4 acc[4];                                                         \
        _Pragma("unroll")                                                     \
        for (int reg = 0; reg < 4; ++reg) {                                   \
            acc[0][reg] = (float)c0[reg]; acc[1][reg] = (float)c1[reg];       \
            acc[2][reg] = (float)c2[reg]; acc[3][reg] = (float)c3[reg];       \
        }                                                                     \
        _Pragma("unroll")                                                     \
        for (int kk = 0; kk < 4; ++kk)                                        \
            _Pragma("unroll")                                                 \
            for (int q = 0; q < 4; ++q)                                       \
                acc[q] = __builtin_amdgcn_mfma_f32_16x16x32_f16(              \
                    afr[kk], bfr[q][kk], acc[q], 0, 0, 0);                    \
        STAGE((s + PH) & 1, s + PH + 2);  /* refill just-consumed buffer */   \
        _Pragma("unroll")                                                     \
        for (int reg = 0; reg < 4; ++reg) {                                   \
            float gi_ = acc[0][reg], gf_ = acc[1][reg];                       \
            float gg_ = acc[2][reg], go_ = acc[3][reg];                       \
            float cn = sigm(gf_) * cst[reg] + sigm(gi_) * tanh_(gg_);         \
            float hn = sigm(go_) * tanh_(cn);                                 \
            if ((unsigned)tb < (unsigned)lenr[reg]) {                         \
                cst[reg] = cn; hst[reg] = hn;                                 \
            }                                                                 \
            HPKC[reg] = (_Float16)hst[reg];                                   \
            int rr = l4 * 4 + reg;                                            \
            unsigned bo = ((unsigned)(rr * 256 + u * 2)) ^                    \
                          (unsigned)((rr & 7) << 4);                          \
            *(_Float16*)((char*)hbuf[(PH) & 1] + bo) = HPKC[reg];             \
        }                                                                     \
        asm volatile("s_waitcnt lgkmcnt(0)" ::: "memory");                    \
        __builtin_amdgcn_s_barrier();                                         \
        asm volatile("" ::: "memory");                                        \
        {                                                                     \
            const unsigned sw2 = (unsigned)((l15 & 7) << 4);                  \
            _Pragma("unroll")                                                 \
            for (int kk = 0; kk < 4; ++kk) {                                  \
                unsigned bo = ((unsigned)(l15 * 256 + kk * 64 + l4 * 16)) ^   \
                              sw2;                                            \
                afr[kk] = *(const f16x8*)((const char*)hbuf[(PH) & 1] + bo);  \
            }                                                                 \
        }                                                                     \
    } while (0)

__global__ __launch_bounds__(512) void lstm_kernel(
    const _Float16* gi, _Float16* hws, const int* __restrict__ lengths,
    const float* __restrict__ Whh_f, const float* __restrict__ Whh_b)
{
    const int bid = blockIdx.x;          // 0..15
    const int dir = bid >> 3;
    const int g   = bid & 7;
    const int tid = threadIdx.x;
    const int w   = tid >> 6;
    const int l   = tid & 63;
    const int l15 = l & 15, l4 = l >> 4;

    __shared__ __align__(16) _Float16 lbuf[2][8192];       // gi double-buffer
    __shared__ __align__(16) _Float16 hbuf[2][kNB * kH];   // h, swizzled

    // ---- Whh B-fragments resident in VGPRs ----
    const float* Whh = dir ? Whh_b : Whh_f;
    f16x8 bfr[4][4];
    #pragma unroll
    for (int q = 0; q < 4; ++q) {
        #pragma unroll
        for (int kk = 0; kk < 4; ++kk) {
            int n  = q * 128 + w * 16 + l15;
            int k0 = kk * 32 + l4 * 8;
            const float* src = Whh + (size_t)n * kH + k0;
            float4 x0 = *(const float4*)(src);
            float4 x1 = *(const float4*)(src + 4);
            f16x8 v;
            v[0] = (_Float16)x0.x; v[1] = (_Float16)x0.y;
            v[2] = (_Float16)x0.z; v[3] = (_Float16)x0.w;
            v[4] = (_Float16)x1.x; v[5] = (_Float16)x1.y;
            v[6] = (_Float16)x1.z; v[7] = (_Float16)x1.w;
            bfr[q][kk] = v;
        }
    }

    int lenr[4];
    #pragma unroll
    for (int reg = 0; reg < 4; ++reg)
        lenr[reg] = lengths[g * kNB + l4 * 4 + reg];
    const int smax = lengths[g * kNB];
    const int smax_pad = (smax + 3) & ~3;

    const int u = w * 16 + l15;
    float cst[4] = {0.f, 0.f, 0.f, 0.f};
    float hst[4] = {0.f, 0.f, 0.f, 0.f};
    f16x8 afr[4];
    #pragma unroll
    for (int kk = 0; kk < 4; ++kk)
        #pragma unroll
        for (int j = 0; j < 8; ++j) afr[kk][j] = (_Float16)0.f;

    const _Float16* grow = gi + (size_t)(dir * 8 + g) * kT * 8192;
    _Float16* hrow_base = hws + (size_t)(dir * 8 + g) * kT * 8192
                              + (size_t)tid * 4;

    // prologue: stage steps 0 and 1, drain, publish
    STAGE(0, 0);
    STAGE(1, 1);
    asm volatile("s_waitcnt vmcnt(0)" ::: "memory");
    __builtin_amdgcn_s_barrier();
    asm volatile("" ::: "memory");

    f16x4 hz; hz[0] = hz[1] = hz[2] = hz[3] = (_Float16)0.f;
    f16x4 hpkA = hz, hpkB = hz, hpkC = hz, hpkD = hz;

    for (int s = 0; s < smax_pad; s += 4) {
        LSTM_BODY(0, hpkD, hpkA, (s > 0));
        LSTM_BODY(1, hpkA, hpkB, 1);
        LSTM_BODY(2, hpkB, hpkC, 1);
        LSTM_BODY(3, hpkC, hpkD, 1);
    }
    {   // epilogue: store last step's h
        int tr = dir ? (smax - smax_pad) : (smax_pad - 1);
        tr = tr < 0 ? 0 : (tr > 511 ? 511 : tr);
        *(f16x4*)(hrow_base + (size_t)tr * 8192) = hpkD;
    }
}

// ---------------------------------------------------------------------------
// Kernel 2b: feats. wg per (g, t): stage both dir h-rows (4KB each) + Wt,
// 144 threads compute fsum[b][t][k] = hf.Wt[:, :128] + hb.Wt[:, 128:] + bt.
// ---------------------------------------------------------------------------
__global__ __launch_bounds__(256) void feats_kernel(
    const _Float16* __restrict__ hws, const float* __restrict__ Wt,
    const float* __restrict__ bt, float* __restrict__ fsum)
{
    __shared__ _Float16 hf[2048], hb[2048];
    __shared__ float wts[kK * 256];
    __shared__ float bts[kK];
    const int g = blockIdx.x >> 9;
    const int t = blockIdx.x & 511;
    const int tid = threadIdx.x;

    *(f16x8*)&hf[tid * 8] =
        *(const f16x8*)(hws + ((size_t)g * kT + t) * 8192 + tid * 8);
    *(f16x8*)&hb[tid * 8] =
        *(const f16x8*)(hws + ((size_t)(8 + g) * kT + t) * 8192 + tid * 8);
    for (int i = tid; i < kK * 256; i += 256) wts[i] = Wt[i];
    if (tid < kK) bts[tid] = bt[tid];
    __syncthreads();

    if (tid < 144) {
        const int k = tid >> 4;      // 0..8
        const int r = tid & 15;      // chain in group
        float acc = bts[k];
        #pragma unroll 8
        for (int uu = 0; uu < kH; ++uu) {
            int idx = (uu >> 4) * 256 + (r >> 2) * 64 + (uu & 15) * 4 + (r & 3);
            acc += (float)hf[idx] * wts[k * 256 + uu] +
                   (float)hb[idx] * wts[k * 256 + 128 + uu];
        }
        fsum[((size_t)(g * 16 + r) * kT + t) * kK + k] = acc;
    }
}

// ---------------------------------------------------------------------------
// Kernel 3: CRF Viterbi via max-plus matrix reduction tree.
// ---------------------------------------------------------------------------
__global__ __launch_bounds__(512) void viterbi_kernel(
    const int* __restrict__ lengths, const float* __restrict__ trans,
    const float* __restrict__ fsumg, float* __restrict__ out)
{
    constexpr float NEG = -1e30f;
    constexpr int RA = 0;
    constexpr int RB = 128 * 81;
    const int b = blockIdx.x;
    const int len = lengths[b];
    const int tid = threadIdx.x;

    __shared__ float tree[(128 + 64) * 81];
    __shared__ float fsum[kT * kK];
    __shared__ float trs[81];
    __shared__ float red[16];

    if (tid < 81) trs[tid] = trans[tid];
    for (int idx = tid; idx < len * kK; idx += 512)
        fsum[idx] = fsumg[(size_t)b * kT * kK + idx];
    __syncthreads();

    for (int task = tid; task < 128 * 9; task += 512) {
        int s = task / 9, j = task - s * 9;
        int tb = 4 * s;
        float uu[9];
        #pragma unroll
        for (int m = 0; m < 9; ++m)
            uu[m] = (tb < len) ? (trs[m * 9 + j] + fsum[tb * 9 + m])
                               : ((m == j) ? 0.f : NEG);
        #pragma unroll
        for (int q = 1; q < 4; ++q) {
            int t = tb + q;
            if (t < len) {
                float un[9];
                #pragma unroll
                for (int k = 0; k < 9; ++k) {
                    float v = trs[k * 9] + uu[0];
                    #pragma unroll
                    for (int m = 1; m < 9; ++m)
                        v = fmaxf(v, trs[k * 9 + m] + uu[m]);
                    un[k] = v + fsum[t * 9 + k];
                }
                #pragma unroll
                for (int k = 0; k < 9; ++k) uu[k] = un[k];
            }
        }
        #pragma unroll
        for (int k = 0; k < 9; ++k)
            tree[RA + s * 81 + k * 9 + j] = uu[k];
    }
    __syncthreads();

    int soff = RA, doff = RB;
    for (int np = 64; np >= 1; np >>= 1) {
        for (int idx = tid; idx < np * 81; idx += 512) {
            int s = idx / 81, o = idx - s * 81;
            int k = o / 9, j = o - k * 9;
            const float* A  = tree + soff + (2 * s + 1) * 81;
            const float* Bm = tree + soff + (2 * s) * 81;
            float v = A[k * 9] + Bm[j];
            #pragma unroll
            for (int m = 1; m < 9; ++m)
                v = fmaxf(v, A[k * 9 + m] + Bm[m * 9 + j]);
            tree[doff + s * 81 + o] = v;
        }
        int tmp = soff; soff = doff; doff = tmp;
        __syncthreads();
    }
    if (tid < kK) {
        int k = tid;
        float fv = tree[soff + k * 9 + kSTART];
        #pragma unroll
        for (int j = 0; j < 9; ++j)
            if (j != kSTART) fv = fmaxf(fv, tree[soff + k * 9 + j] - 10000.f);
        red[k] = fv + trs[kSTOP * 9 + k];
    }
    __syncthreads();
    if (tid == 0) {
        float m = red[0];
        #pragma unroll
        for (int k = 1; k < 9; ++k) m = fmaxf(m, red[k]);
        out[b] = m;
    }
}

// ---------------------------------------------------------------------------
extern "C" void kernel_launch(void* const* d_in, const int* in_sizes, int n_in,
                              void* d_out, int out_size, void* d_ws, size_t ws_size,
                              hipStream_t stream) {
    const int*   sentence = (const int*)d_in[0];
    const int*   lengths  = (const int*)d_in[1];
    const float* emb      = (const float*)d_in[2];
    const float* Wih_f    = (const float*)d_in[3];
    const float* Whh_f    = (const float*)d_in[4];
    const float* b_f      = (const float*)d_in[5];
    const float* Wih_b    = (const float*)d_in[6];
    const float* Whh_b    = (const float*)d_in[7];
    const float* b_b      = (const float*)d_in[8];
    const float* Wt       = (const float*)d_in[9];
    const float* bt       = (const float*)d_in[10];
    const float* trans    = (const float*)d_in[11];
    float* out = (float*)d_out;

    char* ws = (char*)d_ws;
    const size_t gi_bytes = (size_t)2 * kB * kT * kG * sizeof(_Float16); // 128 MiB
    _Float16* gi   = (_Float16*)ws;
    _Float16* hws  = (_Float16*)ws;                  // aliases gi row heads
    float*    fsum = (float*)(ws + gi_bytes);        // 2.25 MiB

    proj_kernel<<<512, 256, 0, stream>>>(sentence, lengths, emb,
                                         Wih_f, b_f, Wih_b, b_b, gi);
    lstm_kernel<<<16, 512, 0, stream>>>(gi, hws, lengths, Whh_f, Whh_b);
    feats_kernel<<<4096, 256, 0, stream>>>(hws, Wt, bt, fsum);
    viterbi_kernel<<<128, 512, 0, stream>>>(lengths, trans, fsum, out);
}

// Round 9
// 616.491 us; speedup vs baseline: 4.4772x; 1.3239x over previous
//
#include <hip/hip_runtime.h>

typedef float f32x4 __attribute__((ext_vector_type(4)));
typedef _Float16 f16x8 __attribute__((ext_vector_type(8)));
typedef _Float16 f16x4 __attribute__((ext_vector_type(4)));

constexpr int kB = 128;     // batch
constexpr int kT = 512;     // time
constexpr int kD = 256;     // emb dim
constexpr int kG = 512;     // 4*H gates per direction
constexpr int kH = 128;     // hidden
constexpr int kK = 9;       // CRF states
constexpr int kSTART = 7;
constexpr int kSTOP = 8;
constexpr int kNB = 16;     // chains per LSTM workgroup

// gi layout, f16:  [dirg = dir*8+g][t][q(4)][u(128)][r(16)]; row = 8192 f16.
// proj ZERO-FILLS gi for t >= len[chain] -> lstm needs no length masking
// (bwd state stays exactly 0 through the zero region; fwd post-len h is
// garbage-but-bounded and never consumed downstream).
// hws (h output) aliases gi row head [0,2048): stores trail consumption.
// fwd wgs (dirg 0-7) prefetch-overrun upward, bwd wgs (dirg 8-15) downward:
// both stay inside the 16x512-row gi region -> no clamps needed.

// ---------------------------------------------------------------------------
// Kernel 1: embedding gather + input projection (f16 MFMA GEMM)
// ---------------------------------------------------------------------------
__global__ __launch_bounds__(256) void proj_kernel(
    const int* __restrict__ sentence, const int* __restrict__ lengths,
    const float* __restrict__ emb,
    const float* __restrict__ Wih_f, const float* __restrict__ b_f,
    const float* __restrict__ Wih_b, const float* __restrict__ b_b,
    _Float16* __restrict__ gi)
{
    __shared__ __align__(16) _Float16 smemA[128 * 256]; // rows=(t,chain), 512B
    __shared__ __align__(16) _Float16 smemW[128 * 256]; // rows=gate, 512B

    const int g  = blockIdx.x >> 6;
    const int tc = blockIdx.x & 63;
    if (tc * 8 >= lengths[g * 16]) return;   // whole 8-t chunk beyond group max
    const int tid = threadIdx.x;

    // ---- stage A once: row = t_local*16 + chain ----
    {
        const int row = tid >> 1;
        const int kb  = (tid & 1) << 7;
        const int b   = g * 16 + (row & 15);
        const int t   = tc * 8 + (row >> 4);
        const int vocab = sentence[b * kT + t];
        const float* src = emb + (size_t)vocab * kD + kb;
        const unsigned rowbyte = row * 512;
        const unsigned sw = (row & 7) << 4;
        #pragma unroll
        for (int c = 0; c < 16; ++c) {
            float4 x0 = *(const float4*)(src + c * 8);
            float4 x1 = *(const float4*)(src + c * 8 + 4);
            f16x8 pk;
            pk[0] = (_Float16)x0.x; pk[1] = (_Float16)x0.y;
            pk[2] = (_Float16)x0.z; pk[3] = (_Float16)x0.w;
            pk[4] = (_Float16)x1.x; pk[5] = (_Float16)x1.y;
            pk[6] = (_Float16)x1.z; pk[7] = (_Float16)x1.w;
            unsigned byteoff = rowbyte + ((unsigned)((kb + c * 8) * 2) ^ sw);
            *(f16x8*)((char*)smemA + byteoff) = pk;
        }
    }

    const int w    = tid >> 6;
    const int lane = tid & 63;
    const int wr = w >> 1, wc = w & 1;
    const int l15 = lane & 15, l4 = lane >> 4;

    // per-lane chain lengths for zero-fill (chains l4*4 .. l4*4+3)
    int lene[4];
    #pragma unroll
    for (int rg = 0; rg < 4; ++rg)
        lene[rg] = lengths[g * 16 + l4 * 4 + rg];

    for (int by = 0; by < 8; ++by) {
        const int dir = by >> 2;
        const int q   = by & 3;
        __syncthreads();     // previous compute done (and A staged, iter 0)
        // ---- stage W rows for this (dir,q) ----
        {
            const int row = tid >> 1;
            const int kb  = (tid & 1) << 7;
            const float* src = (dir == 0 ? Wih_f : Wih_b)
                               + (size_t)(q * 128 + row) * kD + kb;
            const unsigned rowbyte = row * 512;
            const unsigned sw = (row & 7) << 4;
            #pragma unroll
            for (int c = 0; c < 16; ++c) {
                float4 x0 = *(const float4*)(src + c * 8);
                float4 x1 = *(const float4*)(src + c * 8 + 4);
                f16x8 pk;
                pk[0] = (_Float16)x0.x; pk[1] = (_Float16)x0.y;
                pk[2] = (_Float16)x0.z; pk[3] = (_Float16)x0.w;
                pk[4] = (_Float16)x1.x; pk[5] = (_Float16)x1.y;
                pk[6] = (_Float16)x1.z; pk[7] = (_Float16)x1.w;
                unsigned byteoff = rowbyte + ((unsigned)((kb + c * 8) * 2) ^ sw);
                *(f16x8*)((char*)smemW + byteoff) = pk;
            }
        }
        __syncthreads();

        f32x4 zero = {0.f, 0.f, 0.f, 0.f};
        f32x4 acc[4][4];
        #pragma unroll
        for (int mf = 0; mf < 4; ++mf)
            #pragma unroll
            for (int nf = 0; nf < 4; ++nf) acc[mf][nf] = zero;

        #pragma unroll
        for (int kk = 0; kk < 8; ++kk) {
            f16x8 afr[4], bfr[4];
            #pragma unroll
            for (int mf = 0; mf < 4; ++mf) {
                int row = wr * 64 + mf * 16 + l15;
                unsigned byteoff = row * 512 +
                    ((unsigned)(kk * 64 + l4 * 16) ^ (unsigned)((row & 7) << 4));
                afr[mf] = *(const f16x8*)((const char*)smemA + byteoff);
            }
            #pragma unroll
            for (int nf = 0; nf < 4; ++nf) {
                int row = wc * 64 + nf * 16 + l15;
                unsigned byteoff = row * 512 +
                    ((unsigned)(kk * 64 + l4 * 16) ^ (unsigned)((row & 7) << 4));
                bfr[nf] = *(const f16x8*)((const char*)smemW + byteoff);
            }
            #pragma unroll
            for (int mf = 0; mf < 4; ++mf)
                #pragma unroll
                for (int nf = 0; nf < 4; ++nf)
                    acc[mf][nf] = __builtin_amdgcn_mfma_f32_16x16x32_f16(
                        afr[mf], bfr[nf], acc[mf][nf], 0, 0, 0);
        }

        // ---- epilogue: one f16x4 (8B) store per fragment; zero for t>=len ---
        const float* biasp = (dir == 0) ? b_f : b_b;
        _Float16* dbase = gi + (size_t)(dir * 8 + g) * kT * 8192;
        #pragma unroll
        for (int nf = 0; nf < 4; ++nf) {
            int u = wc * 64 + nf * 16 + l15;
            float bias = biasp[q * 128 + u];
            #pragma unroll
            for (int mf = 0; mf < 4; ++mf) {
                int t = tc * 8 + wr * 4 + mf;
                f16x4 pk;
                #pragma unroll
                for (int rg = 0; rg < 4; ++rg) {
                    float v = (t < lene[rg]) ? (acc[mf][nf][rg] + bias) : 0.f;
                    pk[rg] = (_Float16)v;
                }
                *(f16x4*)(dbase + (size_t)t * 8192 + (q * 128 + u) * 16 + l4 * 4) = pk;
            }
        }
    }
}

// ---------------------------------------------------------------------------
// Kernel 2: persistent weight-stationary LSTM. 16 wgs x 512 thr.
// R5 structure (known-best): 4-phase unroll, 4-deep prefetch, counted lgkm
// barrier. Trims: no length masks (gi zero-filled), no g-clamp, merged rcp
// (7 trans/pair), no LOADSET clamps, padded loop + uniform store guard.
// ---------------------------------------------------------------------------
__device__ inline void wg_barrier() {
    asm volatile("s_waitcnt lgkmcnt(0)" ::: "memory");
    __builtin_amdgcn_s_barrier();
    asm volatile("" ::: "memory");
}

#define LOADSET(GP, SS)                                                       \
    do {                                                                      \
        int tt = dir ? (smax - 1 - (SS)) : (SS);                              \
        const _Float16* rp = glane + (ptrdiff_t)tt * 8192;                    \
        GP##0 = *(const f16x4*)(rp);                                          \
        GP##1 = *(const f16x4*)(rp + 2048);                                   \
        GP##2 = *(const f16x4*)(rp + 4096);                                   \
        GP##3 = *(const f16x4*)(rp + 6144);                                   \
    } while (0)

#define ACTIVATE(reg, ACC0, ACC1, ACC2, ACC3, HPK)                            \
    do {                                                                      \
        float i_ = ACC0, f_ = ACC1, g_ = ACC2, o_ = ACC3;                     \
        float Ei = __expf(-i_), Ef = __expf(-f_);                             \
        float Eg = __expf(-2.f * g_), Eo = __expf(-o_);                       \
        float a1 = 1.f + Ei, a2 = 1.f + Eg, a3 = 1.f + Ef;                    \
        float a12 = a1 * a2;                                                  \
        float num = cst[reg] * a12 + (1.f - Eg) * a3;                         \
        float cn = num * __builtin_amdgcn_rcpf(a3 * a12);                     \
        cst[reg] = cn;                                                        \
        float cc = fminf(fmaxf(cn, -15.f), 15.f);                             \
        float Ec = __expf(-2.f * cc);                                         \
        float hn = (1.f - Ec) *                                               \
            __builtin_amdgcn_rcpf((1.f + Eo) * (1.f + Ec));                   \
        HPK[reg] = (_Float16)hn;                                              \
    } while (0)

#define LSTM_BODY(PH, GP)                                                     \
    do {                                                                      \
        const int tb = dir ? (smax - 1 - (s + PH)) : (s + PH);                \
        f32x4 acc[4];                                                         \
        _Pragma("unroll")                                                     \
        for (int reg = 0; reg < 4; ++reg) {                                   \
            acc[0][reg] = (float)GP##0[reg];                                  \
            acc[1][reg] = (float)GP##1[reg];                                  \
            acc[2][reg] = (float)GP##2[reg];                                  \
            acc[3][reg] = (float)GP##3[reg];                                  \
        }                                                                     \
        LOADSET(GP, s + PH + 4);                                              \
        _Pragma("unroll")                                                     \
        for (int kk = 0; kk < 4; ++kk)                                        \
            _Pragma("unroll")                                                 \
            for (int q = 0; q < 4; ++q)                                       \
                acc[q] = __builtin_amdgcn_mfma_f32_16x16x32_f16(              \
                    afr[kk], bfr[q][kk], acc[q], 0, 0, 0);                    \
        f16x4 hpk;                                                            \
        _Pragma("unroll")                                                     \
        for (int reg = 0; reg < 4; ++reg) {                                   \
            ACTIVATE(reg, acc[0][reg], acc[1][reg], acc[2][reg],              \
                     acc[3][reg], hpk);                                       \
            int rr = l4 * 4 + reg;                                            \
            unsigned bo = ((unsigned)(rr * 256 + u * 2)) ^                    \
                          (unsigned)((rr & 7) << 4);                          \
            *(_Float16*)((char*)hbuf[(PH) & 1] + bo) = hpk[reg];              \
        }                                                                     \
        if ((unsigned)tb < (unsigned)smax) {  /* wg-uniform scalar branch */  \
            *(f16x4*)(hrow_base + (size_t)tb * 8192) = hpk;                   \
        }                                                                     \
        wg_barrier();                                                         \
        {                                                                     \
            const unsigned sw2 = (unsigned)((l15 & 7) << 4);                  \
            _Pragma("unroll")                                                 \
            for (int kk = 0; kk < 4; ++kk) {                                  \
                unsigned bo = ((unsigned)(l15 * 256 + kk * 64 + l4 * 16)) ^   \
                              sw2;                                            \
                afr[kk] = *(const f16x8*)((const char*)hbuf[(PH) & 1] + bo);  \
            }                                                                 \
        }                                                                     \
    } while (0)

__global__ __launch_bounds__(512) void lstm_kernel(
    const _Float16* gi, _Float16* hws, const int* __restrict__ lengths,
    const float* __restrict__ Whh_f, const float* __restrict__ Whh_b)
{
    const int bid = blockIdx.x;          // 0..15
    const int dir = bid >> 3;
    const int g   = bid & 7;
    const int tid = threadIdx.x;
    const int w   = tid >> 6;
    const int l   = tid & 63;
    const int l15 = l & 15, l4 = l >> 4;

    __shared__ __align__(16) _Float16 hbuf[2][kNB * kH];

    // ---- Whh B-fragments resident in VGPRs ----
    const float* Whh = dir ? Whh_b : Whh_f;
    f16x8 bfr[4][4];
    #pragma unroll
    for (int q = 0; q < 4; ++q) {
        #pragma unroll
        for (int kk = 0; kk < 4; ++kk) {
            int n  = q * 128 + w * 16 + l15;
            int k0 = kk * 32 + l4 * 8;
            const float* src = Whh + (size_t)n * kH + k0;
            float4 x0 = *(const float4*)(src);
            float4 x1 = *(const float4*)(src + 4);
            f16x8 v;
            v[0] = (_Float16)x0.x; v[1] = (_Float16)x0.y;
            v[2] = (_Float16)x0.z; v[3] = (_Float16)x0.w;
            v[4] = (_Float16)x1.x; v[5] = (_Float16)x1.y;
            v[6] = (_Float16)x1.z; v[7] = (_Float16)x1.w;
            bfr[q][kk] = v;
        }
    }

    const int smax = lengths[g * kNB];
    const int smax_pad = (smax + 3) & ~3;

    const int u = w * 16 + l15;
    float cst[4] = {0.f, 0.f, 0.f, 0.f};
    f16x8 afr[4];
    #pragma unroll
    for (int kk = 0; kk < 4; ++kk)
        #pragma unroll
        for (int j = 0; j < 8; ++j) afr[kk][j] = (_Float16)0.f;

    const _Float16* glane = gi + (size_t)(dir * 8 + g) * kT * 8192
                               + (size_t)(u * 16 + l4 * 4);
    _Float16* hrow_base = hws + (size_t)(dir * 8 + g) * kT * 8192
                              + (size_t)tid * 4;

    f16x4 gA0, gA1, gA2, gA3, gB0, gB1, gB2, gB3;
    f16x4 gC0, gC1, gC2, gC3, gD0, gD1, gD2, gD3;
    LOADSET(gA, 0); LOADSET(gB, 1); LOADSET(gC, 2); LOADSET(gD, 3);

    for (int s = 0; s < smax_pad; s += 4) {
        LSTM_BODY(0, gA);
        LSTM_BODY(1, gB);
        LSTM_BODY(2, gC);
        LSTM_BODY(3, gD);
    }
}

// ---------------------------------------------------------------------------
// Kernel 2b: feats. wg per (g, t): stage both dir h-rows (4KB each) + Wt,
// 144 threads compute fsum[b][t][k] = hf.Wt[:, :128] + hb.Wt[:, 128:] + bt.
// ---------------------------------------------------------------------------
__global__ __launch_bounds__(256) void feats_kernel(
    const _Float16* __restrict__ hws, const float* __restrict__ Wt,
    const float* __restrict__ bt, float* __restrict__ fsum)
{
    __shared__ _Float16 hf[2048], hb[2048];
    __shared__ float wts[kK * 256];
    __shared__ float bts[kK];
    const int g = blockIdx.x >> 9;
    const int t = blockIdx.x & 511;
    const int tid = threadIdx.x;

    *(f16x8*)&hf[tid * 8] =
        *(const f16x8*)(hws + ((size_t)g * kT + t) * 8192 + tid * 8);
    *(f16x8*)&hb[tid * 8] =
        *(const f16x8*)(hws + ((size_t)(8 + g) * kT + t) * 8192 + tid * 8);
    for (int i = tid; i < kK * 256; i += 256) wts[i] = Wt[i];
    if (tid < kK) bts[tid] = bt[tid];
    __syncthreads();

    if (tid < 144) {
        const int k = tid >> 4;      // 0..8
        const int r = tid & 15;      // chain in group
        float acc = bts[k];
        #pragma unroll 8
        for (int uu = 0; uu < kH; ++uu) {
            int idx = (uu >> 4) * 256 + (r >> 2) * 64 + (uu & 15) * 4 + (r & 3);
            acc += (float)hf[idx] * wts[k * 256 + uu] +
                   (float)hb[idx] * wts[k * 256 + 128 + uu];
        }
        fsum[((size_t)(g * 16 + r) * kT + t) * kK + k] = acc;
    }
}

// ---------------------------------------------------------------------------
// Kernel 3: CRF Viterbi via max-plus matrix reduction tree.
// ---------------------------------------------------------------------------
__global__ __launch_bounds__(512) void viterbi_kernel(
    const int* __restrict__ lengths, const float* __restrict__ trans,
    const float* __restrict__ fsumg, float* __restrict__ out)
{
    constexpr float NEG = -1e30f;
    constexpr int RA = 0;
    constexpr int RB = 128 * 81;
    const int b = blockIdx.x;
    const int len = lengths[b];
    const int tid = threadIdx.x;

    __shared__ float tree[(128 + 64) * 81];
    __shared__ float fsum[kT * kK];
    __shared__ float trs[81];
    __shared__ float red[16];

    if (tid < 81) trs[tid] = trans[tid];
    for (int idx = tid; idx < len * kK; idx += 512)
        fsum[idx] = fsumg[(size_t)b * kT * kK + idx];
    __syncthreads();

    for (int task = tid; task < 128 * 9; task += 512) {
        int s = task / 9, j = task - s * 9;
        int tb = 4 * s;
        float uu[9];
        #pragma unroll
        for (int m = 0; m < 9; ++m)
            uu[m] = (tb < len) ? (trs[m * 9 + j] + fsum[tb * 9 + m])
                               : ((m == j) ? 0.f : NEG);
        #pragma unroll
        for (int q = 1; q < 4; ++q) {
            int t = tb + q;
            if (t < len) {
                float un[9];
                #pragma unroll
                for (int k = 0; k < 9; ++k) {
                    float v = trs[k * 9] + uu[0];
                    #pragma unroll
                    for (int m = 1; m < 9; ++m)
                        v = fmaxf(v, trs[k * 9 + m] + uu[m]);
                    un[k] = v + fsum[t * 9 + k];
                }
                #pragma unroll
                for (int k = 0; k < 9; ++k) uu[k] = un[k];
            }
        }
        #pragma unroll
        for (int k = 0; k < 9; ++k)
            tree[RA + s * 81 + k * 9 + j] = uu[k];
    }
    __syncthreads();

    int soff = RA, doff = RB;
    for (int np = 64; np >= 1; np >>= 1) {
        for (int idx = tid; idx < np * 81; idx += 512) {
            int s = idx / 81, o = idx - s * 81;
            int k = o / 9, j = o - k * 9;
            const float* A  = tree + soff + (2 * s + 1) * 81;
            const float* Bm = tree + soff + (2 * s) * 81;
            float v = A[k * 9] + Bm[j];
            #pragma unroll
            for (int m = 1; m < 9; ++m)
                v = fmaxf(v, A[k * 9 + m] + Bm[m * 9 + j]);
            tree[doff + s * 81 + o] = v;
        }
        int tmp = soff; soff = doff; doff = tmp;
        __syncthreads();
    }
    if (tid < kK) {
        int k = tid;
        float fv = tree[soff + k * 9 + kSTART];
        #pragma unroll
        for (int j = 0; j < 9; ++j)
            if (j != kSTART) fv = fmaxf(fv, tree[soff + k * 9 + j] - 10000.f);
        red[k] = fv + trs[kSTOP * 9 + k];
    }
    __syncthreads();
    if (tid == 0) {
        float m = red[0];
        #pragma unroll
        for (int k = 1; k < 9; ++k) m = fmaxf(m, red[k]);
        out[b] = m;
    }
}

// ---------------------------------------------------------------------------
extern "C" void kernel_launch(void* const* d_in, const int* in_sizes, int n_in,
                              void* d_out, int out_size, void* d_ws, size_t ws_size,
                              hipStream_t stream) {
    const int*   sentence = (const int*)d_in[0];
    const int*   lengths  = (const int*)d_in[1];
    const float* emb      = (const float*)d_in[2];
    const float* Wih_f    = (const float*)d_in[3];
    const float* Whh_f    = (const float*)d_in[4];
    const float* b_f      = (const float*)d_in[5];
    const float* Wih_b    = (const float*)d_in[6];
    const float* Whh_b    = (const float*)d_in[7];
    const float* b_b      = (const float*)d_in[8];
    const float* Wt       = (const float*)d_in[9];
    const float* bt       = (const float*)d_in[10];
    const float* trans    = (const float*)d_in[11];
    float* out = (float*)d_out;

    char* ws = (char*)d_ws;
    const size_t gi_bytes = (size_t)2 * kB * kT * kG * sizeof(_Float16); // 128 MiB
    _Float16* gi   = (_Float16*)ws;
    _Float16* hws  = (_Float16*)ws;                  // aliases gi row heads
    float*    fsum = (float*)(ws + gi_bytes);        // 2.25 MiB

    proj_kernel<<<512, 256, 0, stream>>>(sentence, lengths, emb,
                                         Wih_f, b_f, Wih_b, b_b, gi);
    lstm_kernel<<<16, 512, 0, stream>>>(gi, hws, lengths, Whh_f, Whh_b);
    feats_kernel<<<4096, 256, 0, stream>>>(hws, Wt, bt, fsum);
    viterbi_kernel<<<128, 512, 0, stream>>>(lengths, trans, fsum, out);
}